// Round 1
// baseline (110.543 us; speedup 1.0000x reference)
//
#include <hip/hip_runtime.h>
#include <hip/hip_bf16.h>
#include <stdint.h>

// SimCLR loss, B=4096, D=256, T=0.1.
// loss = (1/2B) * sum_i [ log(sum_{j!=i} exp(sim_ij)) - sim_{i,pair(i)} ]
// sim in [-10,10] => no max-subtraction needed.
// R7: MX-scaled fp8 MFMA (16x16x128, scales=1.0) -> 2x MFMA rate AND
// conflict-free b128 LDS fragment reads. A strip resident in VGPRs.
// 544 strip blocks (<=4 consecutive same-bi tiles), B double-buffered.
// Symmetric: lower-triangle tiles; off-diag adds row sums AND col sums.
// R8: remove ALL device-scope atomics from the hot kernel. Row/col sums
// go to private per-(strip,tile,wave-half) workspace slots as plain
// stores; finalize gathers the <=158 partials per row. Theory: 655K
// device-scope fp32 atomicAdds must serialize at the XCD-coherent point
// (per-XCD L2s non-coherent) and are the hidden simexp cost.

#define BROWS 4096
#define NROWS 8192
#define DDIM  256
#define TINV  10.0f
#define LOG2E10 14.4269504088896340736f   // 10 * log2(e)
#define EPSN  1e-8f

#define TM    128
#define NTILE (NROWS / TM)               // 64
#define NBLK  544                        // sum_{m=1..64} ceil(m/4)

typedef float f32x4 __attribute__((ext_vector_type(4)));
typedef int   i32x4 __attribute__((ext_vector_type(4)));
typedef int   i32x8 __attribute__((ext_vector_type(8)));

// ------- prep: norms + fp8 unit rows (pre-swizzled) + pos + out zero -------
// row image: 16 granules of 16B; granule g stored at slot g ^ (row&15).
__global__ __launch_bounds__(256) void prep_kernel(
    const float* __restrict__ z1, const float* __restrict__ z2,
    unsigned int* __restrict__ zn8, float* __restrict__ pos,
    float* __restrict__ out) {
  int t = threadIdx.x;
  int i    = blockIdx.x * 4 + (t >> 6);
  int lane = t & 63;
  if (blockIdx.x == 0 && t == 0) out[0] = 0.f;

  float4 a = ((const float4*)(z1 + (size_t)i * DDIM))[lane];
  float4 b = ((const float4*)(z2 + (size_t)i * DDIM))[lane];
  float s1 = a.x*a.x + a.y*a.y + a.z*a.z + a.w*a.w;
  float s2 = b.x*b.x + b.y*b.y + b.z*b.z + b.w*b.w;
  float dt = a.x*b.x + a.y*b.y + a.z*b.z + a.w*b.w;
  #pragma unroll
  for (int off = 32; off; off >>= 1) {
    s1 += __shfl_xor(s1, off, 64);
    s2 += __shfl_xor(s2, off, 64);
    dt += __shfl_xor(dt, off, 64);
  }
  float i1 = 1.0f / fmaxf(sqrtf(s1), EPSN);
  float i2 = 1.0f / fmaxf(sqrtf(s2), EPSN);
  if (lane == 0) pos[i] = dt * i1 * i2 * TINV;
  int p1 = __builtin_amdgcn_cvt_pk_fp8_f32(a.x*i1, a.y*i1, 0, false);
  p1     = __builtin_amdgcn_cvt_pk_fp8_f32(a.z*i1, a.w*i1, p1, true);
  int p2 = __builtin_amdgcn_cvt_pk_fp8_f32(b.x*i2, b.y*i2, 0, false);
  p2     = __builtin_amdgcn_cvt_pk_fp8_f32(b.z*i2, b.w*i2, p2, true);
  int g16 = lane >> 2, b4 = lane & 3;
  int slot = g16 ^ (i & 15);                 // (i+BROWS)&15 == i&15
  zn8[(size_t)i * 64 + slot * 4 + b4]           = (unsigned int)p1;
  zn8[(size_t)(i + BROWS) * 64 + slot * 4 + b4] = (unsigned int)p2;
}

// ---------------- async global->LDS, 16B (contiguous) ----------------------
__device__ __forceinline__ void async16(const unsigned char* g, unsigned char* l) {
  __builtin_amdgcn_global_load_lds(
      (const __attribute__((address_space(1))) unsigned int*)g,
      (__attribute__((address_space(3))) unsigned int*)l,
      16, 0, 0);
}

// ---------------- strip Gram + exp + row/col partial sums ------------------
__global__ __launch_bounds__(256, 2) void simexp_kernel(
    const unsigned char* __restrict__ zn8,
    float* __restrict__ part_row, float* __restrict__ part_col) {
  __shared__ __align__(16) unsigned char lds[2][TM * 256];  // 2 x 32 KB

  // block -> (bi, bj0, nt): row bi has ceil((bi+1)/4) groups of <=4 tiles
  int b = blockIdx.x;
  int bi = 0, cum = 0;
  for (;;) { int ng = (bi + 4) >> 2; if (cum + ng > b) break; cum += ng; ++bi; }
  const int bj0 = (b - cum) * 4;
  const int nt  = min(bi - bj0 + 1, 4);

  const int t = threadIdx.x;
  const int wave = t >> 6, lane = t & 63;
  const int wr = wave >> 1, wc = wave & 1;
  const int quad = lane >> 4, l15 = lane & 15;
  const int rowA0 = bi * TM;

  auto stage = [&](const unsigned char* gbase, int buf) {
    #pragma unroll
    for (int p = 0; p < 8; ++p) {
      int j = p * 256 + t;
      async16(gbase + (size_t)j * 16, &lds[buf][j * 16]);
    }
  };

  // stage A -> buf1, B0 -> buf0
  stage(zn8 + (size_t)rowA0 * 256, 1);
  stage(zn8 + (size_t)(bj0 * TM) * 256, 0);
  __syncthreads();

  // extract A fragments to VGPRs: afr[mi][kb] = 32 k-bytes of row
  // (rowA0 + wr*64 + mi*16 + l15), k in [kb*128 + quad*32, +32)
  i32x8 afr[4][2];
  #pragma unroll
  for (int mi = 0; mi < 4; ++mi) {
    int row = wr * 64 + mi * 16 + l15;
    const unsigned char* rbase = &lds[1][row * 256];
    #pragma unroll
    for (int kb = 0; kb < 2; ++kb) {
      int g0 = kb * 8 + quad * 2;
      i32x4 lo = *(const i32x4*)(rbase + ((g0 ^ (row & 15)) << 4));
      i32x4 hi = *(const i32x4*)(rbase + (((g0 + 1) ^ (row & 15)) << 4));
      afr[mi][kb][0] = lo[0]; afr[mi][kb][1] = lo[1];
      afr[mi][kb][2] = lo[2]; afr[mi][kb][3] = lo[3];
      afr[mi][kb][4] = hi[0]; afr[mi][kb][5] = hi[1];
      afr[mi][kb][6] = hi[2]; afr[mi][kb][7] = hi[3];
    }
  }
  __syncthreads();                       // buf1 free before B1 DMA
  if (nt > 1) stage(zn8 + (size_t)((bj0 + 1) * TM) * 256, 1);

  float rs[4][4] = {};                   // strip row sums (regs)

  for (int tix = 0; tix < nt; ++tix) {
    const unsigned char* bb = lds[tix & 1];
    const int bj = bj0 + tix;

    f32x4 acc[4][4] = {};
    #pragma unroll
    for (int kb = 0; kb < 2; ++kb) {
      i32x8 bfr[4];
      #pragma unroll
      for (int nj = 0; nj < 4; ++nj) {
        int row = wc * 64 + nj * 16 + l15;
        const unsigned char* rbase = bb + row * 256;
        int g0 = kb * 8 + quad * 2;
        i32x4 lo = *(const i32x4*)(rbase + ((g0 ^ (row & 15)) << 4));
        i32x4 hi = *(const i32x4*)(rbase + (((g0 + 1) ^ (row & 15)) << 4));
        bfr[nj][0] = lo[0]; bfr[nj][1] = lo[1];
        bfr[nj][2] = lo[2]; bfr[nj][3] = lo[3];
        bfr[nj][4] = hi[0]; bfr[nj][5] = hi[1];
        bfr[nj][6] = hi[2]; bfr[nj][7] = hi[3];
      }
      #pragma unroll
      for (int mi = 0; mi < 4; ++mi)
        #pragma unroll
        for (int nj = 0; nj < 4; ++nj)
          acc[mi][nj] = __builtin_amdgcn_mfma_scale_f32_16x16x128_f8f6f4(
              afr[mi][kb], bfr[nj], acc[mi][nj],
              0, 0,                       // cbsz=fp8(e4m3), blgp=fp8(e4m3)
              0, 0x7F7F7F7F,              // scale_a opsel, scale_a = 1.0
              0, 0x7F7F7F7F);             // scale_b opsel, scale_b = 1.0
    }

    // epilogue: exp2(acc * 10*log2e); diag mask only on the diagonal tile
    float cs[4] = {0.f, 0.f, 0.f, 0.f};
    if (bj == bi) {
      #pragma unroll
      for (int mi = 0; mi < 4; ++mi)
        #pragma unroll
        for (int nj = 0; nj < 4; ++nj) {
          int gj = wc * 64 + nj * 16 + l15;            // tile-local col
          #pragma unroll
          for (int r = 0; r < 4; ++r) {
            int gi = wr * 64 + mi * 16 + quad * 4 + r; // tile-local row
            float e = (gi == gj) ? 0.f : exp2f(acc[mi][nj][r] * LOG2E10);
            rs[mi][r] += e;
          }
        }
    } else {
      #pragma unroll
      for (int mi = 0; mi < 4; ++mi)
        #pragma unroll
        for (int nj = 0; nj < 4; ++nj)
          #pragma unroll
          for (int r = 0; r < 4; ++r) {
            float e = exp2f(acc[mi][nj][r] * LOG2E10);
            rs[mi][r] += e;
            cs[nj] += e;
          }
      // symmetry: column sums -> private partial slot (plain store)
      #pragma unroll
      for (int nj = 0; nj < 4; ++nj) {
        float v = cs[nj];
        v += __shfl_xor(v, 16, 64);
        v += __shfl_xor(v, 32, 64);
        if (quad == 0)
          part_col[(size_t)((b * 4 + tix) * 2 + wr) * 128
                   + wc * 64 + nj * 16 + l15] = v;
      }
    }

    if (tix + 1 < nt) {
      __syncthreads();                   // drains B_{t+1}; frees buf[tix&1]
      if (tix + 2 < nt)
        stage(zn8 + (size_t)((bj0 + tix + 2) * TM) * 256, tix & 1);
    }
  }

  // strip row sums -> private partial slot (one store per row per wc)
  #pragma unroll
  for (int mi = 0; mi < 4; ++mi)
    #pragma unroll
    for (int r = 0; r < 4; ++r) {
      float v = rs[mi][r];
      v += __shfl_xor(v, 1, 64);
      v += __shfl_xor(v, 2, 64);
      v += __shfl_xor(v, 4, 64);
      v += __shfl_xor(v, 8, 64);
      if (l15 == 0)
        part_row[(size_t)(b * 2 + wc) * 128
                 + wr * 64 + mi * 16 + quad * 4 + r] = v;
    }
}

// --------- final: gather partials per row, log, reduce (32 blocks) ---------
__global__ __launch_bounds__(256) void finalize_kernel(
    const float* __restrict__ part_row, const float* __restrict__ part_col,
    const float* __restrict__ pos, float* __restrict__ out) {
  __shared__ float red[4];
  int t = threadIdx.x;
  int idx = blockIdx.x * 256 + t;        // global row (wave-uniform br)
  int br = idx >> 7, r = idx & 127;

  float s0 = 0.f, s1 = 0.f;
  int cum = 0, cumbr = 0;
  for (int bi = 0; bi < 64; ++bi) {
    if (bi == br) cumbr = cum;
    if (bi > br) {
      // tile (bi, br) lives in strip (bi, g=br>>2) at tix=br&3
      int slot = ((cum + (br >> 2)) * 4 + (br & 3)) * 2;
      s0 += part_col[(size_t)(slot + 0) * 128 + r];
      s1 += part_col[(size_t)(slot + 1) * 128 + r];
    }
    cum += (bi + 4) >> 2;
  }
  int ngbr = (br + 4) >> 2;              // strips of own row-block
  for (int g = 0; g < ngbr; ++g) {
    s0 += part_row[(size_t)((cumbr + g) * 2 + 0) * 128 + r];
    s1 += part_row[(size_t)((cumbr + g) * 2 + 1) * 128 + r];
  }

  float s = __logf(s0 + s1);
  if (idx < BROWS) s -= 2.f * pos[idx];
  #pragma unroll
  for (int off = 32; off; off >>= 1) s += __shfl_xor(s, off, 64);
  if ((t & 63) == 0) red[t >> 6] = s;
  __syncthreads();
  if (t == 0)
    atomicAdd(out, (red[0] + red[1] + red[2] + red[3]) / (float)NROWS);
}

// ---------------- launch ----------------------------------------------------
extern "C" void kernel_launch(void* const* d_in, const int* in_sizes, int n_in,
                              void* d_out, int out_size, void* d_ws, size_t ws_size,
                              hipStream_t stream) {
  const float* z1 = (const float*)d_in[0];
  const float* z2 = (const float*)d_in[1];
  char* ws = (char*)d_ws;
  unsigned int* zn8 = (unsigned int*)ws;                   // 2 MB (fp8 rows)
  float* part_row = (float*)(ws + 2097152);                // 544*2*128*4   = 557056 B
  float* part_col = (float*)(ws + 2654208);                // 544*4*2*128*4 = 2228224 B
  float* pos      = (float*)(ws + 4882432);                // 16 KB
  float* out      = (float*)d_out;

  prep_kernel<<<BROWS / 4, 256, 0, stream>>>(z1, z2, zn8, pos, out);
  simexp_kernel<<<NBLK, 256, 0, stream>>>((const unsigned char*)zn8,
                                          part_row, part_col);
  finalize_kernel<<<NROWS / 256, 256, 0, stream>>>(part_row, part_col, pos, out);
}

// Round 2
// 95.406 us; speedup vs baseline: 1.1587x; 1.1587x over previous
//
#include <hip/hip_runtime.h>
#include <hip/hip_bf16.h>
#include <stdint.h>

// SimCLR loss, B=4096, D=256, T=0.1.
// loss = (1/2B) * sum_i [ log(sum_{j!=i} exp(sim_ij)) - sim_{i,pair(i)} ]
// sim in [-10,10] => no max-subtraction needed.
// R7: MX-scaled fp8 MFMA (16x16x128, scales=1.0) -> 2x MFMA rate AND
// conflict-free b128 LDS fragment reads. A strip resident in VGPRs.
// 544 strip blocks (<=4 consecutive same-bi tiles), B double-buffered.
// Symmetric: lower-triangle tiles; off-diag adds row sums AND col sums.
// R8: atomics -> private partial-slot stores. simexp unchanged-or-better;
// but the 32-block gather was latency-bound (64 serial cross-XCD loads,
// 1 wave/SIMD) => +17us. R9: two-stage gather: 1024 blocks x 128 thr,
// closed-form strip indexing (cum(bi) = bi + 2q(q-1) + q*rr), <=10
// independent coalesced loads/thread -> 16 partial planes; finalize
// sums 16 planes + log + reduce. Every workspace slot written each run
// (poison-safe).

#define BROWS 4096
#define NROWS 8192
#define DDIM  256
#define TINV  10.0f
#define LOG2E10 14.4269504088896340736f   // 10 * log2(e)
#define EPSN  1e-8f

#define TM    128
#define NTILE (NROWS / TM)               // 64
#define NBLK  544                        // sum_{m=1..64} ceil(m/4)

typedef float f32x4 __attribute__((ext_vector_type(4)));
typedef int   i32x4 __attribute__((ext_vector_type(4)));
typedef int   i32x8 __attribute__((ext_vector_type(8)));

// ------- prep: norms + fp8 unit rows (pre-swizzled) + pos + out zero -------
// row image: 16 granules of 16B; granule g stored at slot g ^ (row&15).
__global__ __launch_bounds__(256) void prep_kernel(
    const float* __restrict__ z1, const float* __restrict__ z2,
    unsigned int* __restrict__ zn8, float* __restrict__ pos,
    float* __restrict__ out) {
  int t = threadIdx.x;
  int i    = blockIdx.x * 4 + (t >> 6);
  int lane = t & 63;
  if (blockIdx.x == 0 && t == 0) out[0] = 0.f;

  float4 a = ((const float4*)(z1 + (size_t)i * DDIM))[lane];
  float4 b = ((const float4*)(z2 + (size_t)i * DDIM))[lane];
  float s1 = a.x*a.x + a.y*a.y + a.z*a.z + a.w*a.w;
  float s2 = b.x*b.x + b.y*b.y + b.z*b.z + b.w*b.w;
  float dt = a.x*b.x + a.y*b.y + a.z*b.z + a.w*b.w;
  #pragma unroll
  for (int off = 32; off; off >>= 1) {
    s1 += __shfl_xor(s1, off, 64);
    s2 += __shfl_xor(s2, off, 64);
    dt += __shfl_xor(dt, off, 64);
  }
  float i1 = 1.0f / fmaxf(sqrtf(s1), EPSN);
  float i2 = 1.0f / fmaxf(sqrtf(s2), EPSN);
  if (lane == 0) pos[i] = dt * i1 * i2 * TINV;
  int p1 = __builtin_amdgcn_cvt_pk_fp8_f32(a.x*i1, a.y*i1, 0, false);
  p1     = __builtin_amdgcn_cvt_pk_fp8_f32(a.z*i1, a.w*i1, p1, true);
  int p2 = __builtin_amdgcn_cvt_pk_fp8_f32(b.x*i2, b.y*i2, 0, false);
  p2     = __builtin_amdgcn_cvt_pk_fp8_f32(b.z*i2, b.w*i2, p2, true);
  int g16 = lane >> 2, b4 = lane & 3;
  int slot = g16 ^ (i & 15);                 // (i+BROWS)&15 == i&15
  zn8[(size_t)i * 64 + slot * 4 + b4]           = (unsigned int)p1;
  zn8[(size_t)(i + BROWS) * 64 + slot * 4 + b4] = (unsigned int)p2;
}

// ---------------- async global->LDS, 16B (contiguous) ----------------------
__device__ __forceinline__ void async16(const unsigned char* g, unsigned char* l) {
  __builtin_amdgcn_global_load_lds(
      (const __attribute__((address_space(1))) unsigned int*)g,
      (__attribute__((address_space(3))) unsigned int*)l,
      16, 0, 0);
}

// ---------------- strip Gram + exp + row/col partial sums ------------------
__global__ __launch_bounds__(256, 2) void simexp_kernel(
    const unsigned char* __restrict__ zn8,
    float* __restrict__ part_row, float* __restrict__ part_col) {
  __shared__ __align__(16) unsigned char lds[2][TM * 256];  // 2 x 32 KB

  // block -> (bi, bj0, nt): row bi has ceil((bi+1)/4) groups of <=4 tiles
  int b = blockIdx.x;
  int bi = 0, cum = 0;
  for (;;) { int ng = (bi + 4) >> 2; if (cum + ng > b) break; cum += ng; ++bi; }
  const int bj0 = (b - cum) * 4;
  const int nt  = min(bi - bj0 + 1, 4);

  const int t = threadIdx.x;
  const int wave = t >> 6, lane = t & 63;
  const int wr = wave >> 1, wc = wave & 1;
  const int quad = lane >> 4, l15 = lane & 15;
  const int rowA0 = bi * TM;

  auto stage = [&](const unsigned char* gbase, int buf) {
    #pragma unroll
    for (int p = 0; p < 8; ++p) {
      int j = p * 256 + t;
      async16(gbase + (size_t)j * 16, &lds[buf][j * 16]);
    }
  };

  // stage A -> buf1, B0 -> buf0
  stage(zn8 + (size_t)rowA0 * 256, 1);
  stage(zn8 + (size_t)(bj0 * TM) * 256, 0);
  __syncthreads();

  // extract A fragments to VGPRs: afr[mi][kb] = 32 k-bytes of row
  // (rowA0 + wr*64 + mi*16 + l15), k in [kb*128 + quad*32, +32)
  i32x8 afr[4][2];
  #pragma unroll
  for (int mi = 0; mi < 4; ++mi) {
    int row = wr * 64 + mi * 16 + l15;
    const unsigned char* rbase = &lds[1][row * 256];
    #pragma unroll
    for (int kb = 0; kb < 2; ++kb) {
      int g0 = kb * 8 + quad * 2;
      i32x4 lo = *(const i32x4*)(rbase + ((g0 ^ (row & 15)) << 4));
      i32x4 hi = *(const i32x4*)(rbase + (((g0 + 1) ^ (row & 15)) << 4));
      afr[mi][kb][0] = lo[0]; afr[mi][kb][1] = lo[1];
      afr[mi][kb][2] = lo[2]; afr[mi][kb][3] = lo[3];
      afr[mi][kb][4] = hi[0]; afr[mi][kb][5] = hi[1];
      afr[mi][kb][6] = hi[2]; afr[mi][kb][7] = hi[3];
    }
  }
  __syncthreads();                       // buf1 free before B1 DMA
  if (nt > 1) stage(zn8 + (size_t)((bj0 + 1) * TM) * 256, 1);

  float rs[4][4] = {};                   // strip row sums (regs)

  for (int tix = 0; tix < nt; ++tix) {
    const unsigned char* bb = lds[tix & 1];
    const int bj = bj0 + tix;

    f32x4 acc[4][4] = {};
    #pragma unroll
    for (int kb = 0; kb < 2; ++kb) {
      i32x8 bfr[4];
      #pragma unroll
      for (int nj = 0; nj < 4; ++nj) {
        int row = wc * 64 + nj * 16 + l15;
        const unsigned char* rbase = bb + row * 256;
        int g0 = kb * 8 + quad * 2;
        i32x4 lo = *(const i32x4*)(rbase + ((g0 ^ (row & 15)) << 4));
        i32x4 hi = *(const i32x4*)(rbase + (((g0 + 1) ^ (row & 15)) << 4));
        bfr[nj][0] = lo[0]; bfr[nj][1] = lo[1];
        bfr[nj][2] = lo[2]; bfr[nj][3] = lo[3];
        bfr[nj][4] = hi[0]; bfr[nj][5] = hi[1];
        bfr[nj][6] = hi[2]; bfr[nj][7] = hi[3];
      }
      #pragma unroll
      for (int mi = 0; mi < 4; ++mi)
        #pragma unroll
        for (int nj = 0; nj < 4; ++nj)
          acc[mi][nj] = __builtin_amdgcn_mfma_scale_f32_16x16x128_f8f6f4(
              afr[mi][kb], bfr[nj], acc[mi][nj],
              0, 0,                       // cbsz=fp8(e4m3), blgp=fp8(e4m3)
              0, 0x7F7F7F7F,              // scale_a opsel, scale_a = 1.0
              0, 0x7F7F7F7F);             // scale_b opsel, scale_b = 1.0
    }

    // epilogue: exp2(acc * 10*log2e); diag mask only on the diagonal tile
    float cs[4] = {0.f, 0.f, 0.f, 0.f};
    if (bj == bi) {
      #pragma unroll
      for (int mi = 0; mi < 4; ++mi)
        #pragma unroll
        for (int nj = 0; nj < 4; ++nj) {
          int gj = wc * 64 + nj * 16 + l15;            // tile-local col
          #pragma unroll
          for (int r = 0; r < 4; ++r) {
            int gi = wr * 64 + mi * 16 + quad * 4 + r; // tile-local row
            float e = (gi == gj) ? 0.f : exp2f(acc[mi][nj][r] * LOG2E10);
            rs[mi][r] += e;
          }
        }
    } else {
      #pragma unroll
      for (int mi = 0; mi < 4; ++mi)
        #pragma unroll
        for (int nj = 0; nj < 4; ++nj)
          #pragma unroll
          for (int r = 0; r < 4; ++r) {
            float e = exp2f(acc[mi][nj][r] * LOG2E10);
            rs[mi][r] += e;
            cs[nj] += e;
          }
      // symmetry: column sums -> private partial slot (plain store)
      #pragma unroll
      for (int nj = 0; nj < 4; ++nj) {
        float v = cs[nj];
        v += __shfl_xor(v, 16, 64);
        v += __shfl_xor(v, 32, 64);
        if (quad == 0)
          part_col[(size_t)((b * 4 + tix) * 2 + wr) * 128
                   + wc * 64 + nj * 16 + l15] = v;
      }
    }

    if (tix + 1 < nt) {
      __syncthreads();                   // drains B_{t+1}; frees buf[tix&1]
      if (tix + 2 < nt)
        stage(zn8 + (size_t)((bj0 + tix + 2) * TM) * 256, tix & 1);
    }
  }

  // strip row sums -> private partial slot (one store per row per wc)
  #pragma unroll
  for (int mi = 0; mi < 4; ++mi)
    #pragma unroll
    for (int r = 0; r < 4; ++r) {
      float v = rs[mi][r];
      v += __shfl_xor(v, 1, 64);
      v += __shfl_xor(v, 2, 64);
      v += __shfl_xor(v, 4, 64);
      v += __shfl_xor(v, 8, 64);
      if (l15 == 0)
        part_row[(size_t)(b * 2 + wc) * 128
                 + wr * 64 + mi * 16 + quad * 4 + r] = v;
    }
}

// --------- gather stage 1: 64 row-blocks x 16 splits, 128 thr --------------
// cum(bi) = sum_{m<bi} ((m+4)>>2) = bi + 2q(q-1) + q*rr, q=bi>>2, rr=bi&3
__global__ __launch_bounds__(128) void gather_kernel(
    const float* __restrict__ part_row, const float* __restrict__ part_col,
    float* __restrict__ rowsum_p) {
  const int br = blockIdx.x >> 4, k = blockIdx.x & 15;
  const int r = threadIdx.x;
  float s = 0.f;
  // col partials from tiles (j, br), j > br; split: j = br+1+k, step 16.
  // tile (j,br) lives in strip (cum(j) + (br>>2)) at tix = br&3.
  for (int j = br + 1 + k; j < 64; j += 16) {
    int q = j >> 2, rr = j & 3;
    int cumj = j + 2 * q * (q - 1) + q * rr;
    int slot = ((cumj + (br >> 2)) * 4 + (br & 3)) * 2;
    s += part_col[(size_t)(slot + 0) * 128 + r]
       + part_col[(size_t)(slot + 1) * 128 + r];
  }
  // row partials: strip g == k of row-block br (ngbr <= 16 so one g/split)
  {
    int q = br >> 2, rr = br & 3;
    int cumbr = br + 2 * q * (q - 1) + q * rr;
    int ngbr = (br + 4) >> 2;
    if (k < ngbr) {
      int bslot = (cumbr + k) * 2;
      s += part_row[(size_t)(bslot + 0) * 128 + r]
         + part_row[(size_t)(bslot + 1) * 128 + r];
    }
  }
  rowsum_p[(size_t)k * NROWS + br * 128 + r] = s;   // every slot written
}

// --------- final: sum 16 planes, log, reduce (32 blocks) -------------------
__global__ __launch_bounds__(256) void finalize_kernel(
    const float* __restrict__ rowsum_p, const float* __restrict__ pos,
    float* __restrict__ out) {
  __shared__ float red[4];
  int t = threadIdx.x;
  int idx = blockIdx.x * 256 + t;
  float s = 0.f;
  #pragma unroll
  for (int kk = 0; kk < 16; ++kk)
    s += rowsum_p[(size_t)kk * NROWS + idx];
  float v = __logf(s);
  if (idx < BROWS) v -= 2.f * pos[idx];
  #pragma unroll
  for (int off = 32; off; off >>= 1) v += __shfl_xor(v, off, 64);
  if ((t & 63) == 0) red[t >> 6] = v;
  __syncthreads();
  if (t == 0)
    atomicAdd(out, (red[0] + red[1] + red[2] + red[3]) / (float)NROWS);
}

// ---------------- launch ----------------------------------------------------
extern "C" void kernel_launch(void* const* d_in, const int* in_sizes, int n_in,
                              void* d_out, int out_size, void* d_ws, size_t ws_size,
                              hipStream_t stream) {
  const float* z1 = (const float*)d_in[0];
  const float* z2 = (const float*)d_in[1];
  char* ws = (char*)d_ws;
  unsigned int* zn8 = (unsigned int*)ws;                   // 2 MB (fp8 rows)
  float* part_row = (float*)(ws + 2097152);                // 544*2*128*4   = 557056 B
  float* part_col = (float*)(ws + 2654208);                // 544*4*2*128*4 = 2228224 B
  float* pos      = (float*)(ws + 4882432);                // 16 KB
  float* rowsum_p = (float*)(ws + 4898816);                // 16*8192*4 = 512 KB
  float* out      = (float*)d_out;

  prep_kernel<<<BROWS / 4, 256, 0, stream>>>(z1, z2, zn8, pos, out);
  simexp_kernel<<<NBLK, 256, 0, stream>>>((const unsigned char*)zn8,
                                          part_row, part_col);
  gather_kernel<<<64 * 16, 128, 0, stream>>>(part_row, part_col, rowsum_p);
  finalize_kernel<<<NROWS / 256, 256, 0, stream>>>(rowsum_p, pos, out);
}

// Round 3
// 93.653 us; speedup vs baseline: 1.1803x; 1.0187x over previous
//
#include <hip/hip_runtime.h>
#include <hip/hip_bf16.h>
#include <stdint.h>

// SimCLR loss, B=4096, D=256, T=0.1.
// loss = (1/2B) * sum_i [ log(sum_{j!=i} exp(sim_ij)) - sim_{i,pair(i)} ]
// sim in [-10,10] => no max-subtraction needed.
// R7: MX-scaled fp8 MFMA (16x16x128, scales=1.0) -> 2x MFMA rate AND
// conflict-free b128 LDS fragment reads. A strip resident in VGPRs.
// 544 strip blocks (<=4 consecutive same-bi tiles), B double-buffered
// (2x32KB LDS; A borrows buf1 before the B stream starts).
// Symmetric: lower-triangle tiles; off-diag adds row sums AND col sums.
// R8/R9 post-mortem: timed window = ~84us of harness poison fills
// (2 x 268MB @ 80% HBM peak) + ~10us kernels. Atomics were never the
// bottleneck (R8 store-variant == atomic variant on simexp; R9's extra
// gather launch costs +1.8us). R10: restore the verified-best R0
// 3-launch atomic pipeline.

#define BROWS 4096
#define NROWS 8192
#define DDIM  256
#define TINV  10.0f
#define LOG2E10 14.4269504088896340736f   // 10 * log2(e)
#define EPSN  1e-8f

#define TM    128
#define NTILE (NROWS / TM)               // 64
#define NBLK  544                        // sum_{m=1..64} ceil(m/4)

typedef float f32x4 __attribute__((ext_vector_type(4)));
typedef int   i32x4 __attribute__((ext_vector_type(4)));
typedef int   i32x8 __attribute__((ext_vector_type(8)));

// ------- prep: norms + fp8 unit rows (pre-swizzled) + pos + zeroing -------
// row image: 16 granules of 16B; granule g stored at slot g ^ (row&15).
__global__ __launch_bounds__(256) void prep_kernel(
    const float* __restrict__ z1, const float* __restrict__ z2,
    unsigned int* __restrict__ zn8, float* __restrict__ pos,
    float* __restrict__ rowsum, float* __restrict__ out) {
  int t = threadIdx.x;
  int i    = blockIdx.x * 4 + (t >> 6);
  int lane = t & 63;
  if (blockIdx.x < 32) rowsum[blockIdx.x * 256 + t] = 0.f;
  if (blockIdx.x == 32 && t == 0) out[0] = 0.f;

  float4 a = ((const float4*)(z1 + (size_t)i * DDIM))[lane];
  float4 b = ((const float4*)(z2 + (size_t)i * DDIM))[lane];
  float s1 = a.x*a.x + a.y*a.y + a.z*a.z + a.w*a.w;
  float s2 = b.x*b.x + b.y*b.y + b.z*b.z + b.w*b.w;
  float dt = a.x*b.x + a.y*b.y + a.z*b.z + a.w*b.w;
  #pragma unroll
  for (int off = 32; off; off >>= 1) {
    s1 += __shfl_xor(s1, off, 64);
    s2 += __shfl_xor(s2, off, 64);
    dt += __shfl_xor(dt, off, 64);
  }
  float i1 = 1.0f / fmaxf(sqrtf(s1), EPSN);
  float i2 = 1.0f / fmaxf(sqrtf(s2), EPSN);
  if (lane == 0) pos[i] = dt * i1 * i2 * TINV;
  int p1 = __builtin_amdgcn_cvt_pk_fp8_f32(a.x*i1, a.y*i1, 0, false);
  p1     = __builtin_amdgcn_cvt_pk_fp8_f32(a.z*i1, a.w*i1, p1, true);
  int p2 = __builtin_amdgcn_cvt_pk_fp8_f32(b.x*i2, b.y*i2, 0, false);
  p2     = __builtin_amdgcn_cvt_pk_fp8_f32(b.z*i2, b.w*i2, p2, true);
  int g16 = lane >> 2, b4 = lane & 3;
  int slot = g16 ^ (i & 15);                 // (i+BROWS)&15 == i&15
  zn8[(size_t)i * 64 + slot * 4 + b4]           = (unsigned int)p1;
  zn8[(size_t)(i + BROWS) * 64 + slot * 4 + b4] = (unsigned int)p2;
}

// ---------------- async global->LDS, 16B (contiguous) ----------------------
__device__ __forceinline__ void async16(const unsigned char* g, unsigned char* l) {
  __builtin_amdgcn_global_load_lds(
      (const __attribute__((address_space(1))) unsigned int*)g,
      (__attribute__((address_space(3))) unsigned int*)l,
      16, 0, 0);
}

// ---------------- strip Gram + exp + row/col sums --------------------------
__global__ __launch_bounds__(256, 2) void simexp_kernel(
    const unsigned char* __restrict__ zn8, float* __restrict__ rowsum) {
  __shared__ __align__(16) unsigned char lds[2][TM * 256];  // 2 x 32 KB

  // block -> (bi, bj0, nt): row bi has ceil((bi+1)/4) groups of <=4 tiles
  int b = blockIdx.x;
  int bi = 0, cum = 0;
  for (;;) { int ng = (bi + 4) >> 2; if (cum + ng > b) break; cum += ng; ++bi; }
  const int bj0 = (b - cum) * 4;
  const int nt  = min(bi - bj0 + 1, 4);

  const int t = threadIdx.x;
  const int wave = t >> 6, lane = t & 63;
  const int wr = wave >> 1, wc = wave & 1;
  const int quad = lane >> 4, l15 = lane & 15;
  const int rowA0 = bi * TM;

  auto stage = [&](const unsigned char* gbase, int buf) {
    #pragma unroll
    for (int p = 0; p < 8; ++p) {
      int j = p * 256 + t;
      async16(gbase + (size_t)j * 16, &lds[buf][j * 16]);
    }
  };

  // stage A -> buf1, B0 -> buf0
  stage(zn8 + (size_t)rowA0 * 256, 1);
  stage(zn8 + (size_t)(bj0 * TM) * 256, 0);
  __syncthreads();

  // extract A fragments to VGPRs: afr[mi][kb] = 32 k-bytes of row
  // (rowA0 + wr*64 + mi*16 + l15), k in [kb*128 + quad*32, +32)
  i32x8 afr[4][2];
  #pragma unroll
  for (int mi = 0; mi < 4; ++mi) {
    int row = wr * 64 + mi * 16 + l15;
    const unsigned char* rbase = &lds[1][row * 256];
    #pragma unroll
    for (int kb = 0; kb < 2; ++kb) {
      int g0 = kb * 8 + quad * 2;
      i32x4 lo = *(const i32x4*)(rbase + ((g0 ^ (row & 15)) << 4));
      i32x4 hi = *(const i32x4*)(rbase + (((g0 + 1) ^ (row & 15)) << 4));
      afr[mi][kb][0] = lo[0]; afr[mi][kb][1] = lo[1];
      afr[mi][kb][2] = lo[2]; afr[mi][kb][3] = lo[3];
      afr[mi][kb][4] = hi[0]; afr[mi][kb][5] = hi[1];
      afr[mi][kb][6] = hi[2]; afr[mi][kb][7] = hi[3];
    }
  }
  __syncthreads();                       // buf1 free before B1 DMA
  if (nt > 1) stage(zn8 + (size_t)((bj0 + 1) * TM) * 256, 1);

  float rs[4][4] = {};                   // strip row sums (regs)

  for (int tix = 0; tix < nt; ++tix) {
    const unsigned char* bb = lds[tix & 1];
    const int bj = bj0 + tix, rowB0 = bj * TM;

    f32x4 acc[4][4] = {};
    #pragma unroll
    for (int kb = 0; kb < 2; ++kb) {
      i32x8 bfr[4];
      #pragma unroll
      for (int nj = 0; nj < 4; ++nj) {
        int row = wc * 64 + nj * 16 + l15;
        const unsigned char* rbase = bb + row * 256;
        int g0 = kb * 8 + quad * 2;
        i32x4 lo = *(const i32x4*)(rbase + ((g0 ^ (row & 15)) << 4));
        i32x4 hi = *(const i32x4*)(rbase + (((g0 + 1) ^ (row & 15)) << 4));
        bfr[nj][0] = lo[0]; bfr[nj][1] = lo[1];
        bfr[nj][2] = lo[2]; bfr[nj][3] = lo[3];
        bfr[nj][4] = hi[0]; bfr[nj][5] = hi[1];
        bfr[nj][6] = hi[2]; bfr[nj][7] = hi[3];
      }
      #pragma unroll
      for (int mi = 0; mi < 4; ++mi)
        #pragma unroll
        for (int nj = 0; nj < 4; ++nj)
          acc[mi][nj] = __builtin_amdgcn_mfma_scale_f32_16x16x128_f8f6f4(
              afr[mi][kb], bfr[nj], acc[mi][nj],
              0, 0,                       // cbsz=fp8(e4m3), blgp=fp8(e4m3)
              0, 0x7F7F7F7F,              // scale_a opsel, scale_a = 1.0
              0, 0x7F7F7F7F);             // scale_b opsel, scale_b = 1.0
    }

    // epilogue: exp2(acc * 10*log2e); diag mask only on the diagonal tile
    float cs[4] = {0.f, 0.f, 0.f, 0.f};
    if (bj == bi) {
      #pragma unroll
      for (int mi = 0; mi < 4; ++mi)
        #pragma unroll
        for (int nj = 0; nj < 4; ++nj) {
          int gj = wc * 64 + nj * 16 + l15;            // tile-local col
          #pragma unroll
          for (int r = 0; r < 4; ++r) {
            int gi = wr * 64 + mi * 16 + quad * 4 + r; // tile-local row
            float e = (gi == gj) ? 0.f : exp2f(acc[mi][nj][r] * LOG2E10);
            rs[mi][r] += e;
            cs[nj] += e;
          }
        }
    } else {
      #pragma unroll
      for (int mi = 0; mi < 4; ++mi)
        #pragma unroll
        for (int nj = 0; nj < 4; ++nj)
          #pragma unroll
          for (int r = 0; r < 4; ++r) {
            float e = exp2f(acc[mi][nj][r] * LOG2E10);
            rs[mi][r] += e;
            cs[nj] += e;
          }
      // symmetry: column sums -> rowsum[gj]
      #pragma unroll
      for (int nj = 0; nj < 4; ++nj) {
        float v = cs[nj];
        v += __shfl_xor(v, 16, 64);
        v += __shfl_xor(v, 32, 64);
        if (quad == 0)
          atomicAdd(&rowsum[rowB0 + wc * 64 + nj * 16 + l15], v);
      }
    }

    if (tix + 1 < nt) {
      __syncthreads();                   // drains B_{t+1}; frees buf[tix&1]
      if (tix + 2 < nt)
        stage(zn8 + (size_t)((bj0 + tix + 2) * TM) * 256, tix & 1);
    }
  }

  // strip row sums -> one atomic per (row, wave-half)
  #pragma unroll
  for (int mi = 0; mi < 4; ++mi)
    #pragma unroll
    for (int r = 0; r < 4; ++r) {
      float v = rs[mi][r];
      v += __shfl_xor(v, 1, 64);
      v += __shfl_xor(v, 2, 64);
      v += __shfl_xor(v, 4, 64);
      v += __shfl_xor(v, 8, 64);
      if (l15 == 0)
        atomicAdd(&rowsum[rowA0 + wr * 64 + mi * 16 + quad * 4 + r], v);
    }
}

// ---------------- final scalar reduction (32 blocks) -----------------------
__global__ __launch_bounds__(256) void finalize_kernel(
    const float* __restrict__ rowsum, const float* __restrict__ pos,
    float* __restrict__ out) {
  __shared__ float red[4];
  int t = threadIdx.x;
  int idx = blockIdx.x * 256 + t;
  float s = __logf(rowsum[idx]);
  if (idx < BROWS) s -= 2.f * pos[idx];
  #pragma unroll
  for (int off = 32; off; off >>= 1) s += __shfl_xor(s, off, 64);
  if ((t & 63) == 0) red[t >> 6] = s;
  __syncthreads();
  if (t == 0)
    atomicAdd(out, (red[0] + red[1] + red[2] + red[3]) / (float)NROWS);
}

// ---------------- launch ----------------------------------------------------
extern "C" void kernel_launch(void* const* d_in, const int* in_sizes, int n_in,
                              void* d_out, int out_size, void* d_ws, size_t ws_size,
                              hipStream_t stream) {
  const float* z1 = (const float*)d_in[0];
  const float* z2 = (const float*)d_in[1];
  char* ws = (char*)d_ws;
  unsigned int* zn8 = (unsigned int*)ws;                   // 2 MB (fp8 rows)
  float* rowsum = (float*)(ws + 2097152);                  // 32 KB
  float* pos    = (float*)(ws + 2097152 + 32768);          // 16 KB
  float* out    = (float*)d_out;

  prep_kernel<<<BROWS / 4, 256, 0, stream>>>(z1, z2, zn8, pos, rowsum, out);
  simexp_kernel<<<NBLK, 256, 0, stream>>>((const unsigned char*)zn8, rowsum);
  finalize_kernel<<<NROWS / 256, 256, 0, stream>>>(rowsum, pos, out);
}